// Round 1
// baseline (2535.503 us; speedup 1.0000x reference)
//
#include <hip/hip_runtime.h>
#include <hip/hip_bf16.h>
#include <math.h>

// LMU-FFT: x(32,4096,256), W_u(1,256), W_h(512,512), H(256,4096) -> h(32,4096,512), h_n(32,512)
// Strategy: fold W_h[:, :256] into H: G = W_h[:,:256] @ H  (512 x 4096).
//   h[b,t,o] = relu( (u[b] * G[o])[t]  +  dot(x[b,t,:], W_h[o,256:]) )
// Convolution done with radix-2 FFT (N=8192) fully in LDS; two real channels per
// complex inverse FFT (re -> o even, im -> o odd).

#define BATCH 32
#define T     4096
#define IND   256
#define HID   512
#define FFT_N 8192
#define FFT_LOG 13

// ---------------- shared-memory FFT (radix-2 DIT, N=8192, 256 threads) ----------------
__device__ void fft_lds(float2* s, int tid, float dir /* -1 fwd, +1 inv */) {
    __syncthreads();
    // bit reversal
    for (int i = tid; i < FFT_N; i += 256) {
        int j = __brev((unsigned)i) >> (32 - FFT_LOG);
        if (j > i) { float2 t = s[i]; s[i] = s[j]; s[j] = t; }
    }
    __syncthreads();
    for (int st = 1; st <= FFT_LOG; ++st) {
        int half = 1 << (st - 1);
        float fm = dir * (float)M_PI / (float)half;   // angle = dir * pi * j / half
        for (int k = tid; k < FFT_N / 2; k += 256) {
            int j  = k & (half - 1);
            int i1 = ((k >> (st - 1)) << st) + j;
            int i2 = i1 + half;
            float ang = fm * (float)j;
            float sn, cs;
            sincosf(ang, &sn, &cs);
            float2 bb = s[i2];
            float tr = cs * bb.x - sn * bb.y;
            float ti = cs * bb.y + sn * bb.x;
            float2 aa = s[i1];
            s[i1] = make_float2(aa.x + tr, aa.y + ti);
            s[i2] = make_float2(aa.x - tr, aa.y - ti);
        }
        __syncthreads();
    }
}

// ---------------- kernel 1: u[b,t] = relu(dot(x[b,t,:], W_u)) ----------------
__global__ __launch_bounds__(256) void relu_u_kernel(const float* __restrict__ x,
                                                     const float* __restrict__ Wu,
                                                     float* __restrict__ u) {
    int wave = threadIdx.x >> 6, lane = threadIdx.x & 63;
    int r = blockIdx.x * 4 + wave;              // 0..131071
    const float4 xv = *(const float4*)(x + (size_t)r * IND + lane * 4);
    const float4 wv = *(const float4*)(Wu + lane * 4);
    float acc = xv.x * wv.x + xv.y * wv.y + xv.z * wv.z + xv.w * wv.w;
    for (int off = 32; off; off >>= 1) acc += __shfl_down(acc, off);
    if (lane == 0) u[r] = fmaxf(acc, 0.f);
}

// ---------------- kernel 2: U[b] = FFT_8192(zero-pad u[b]) ----------------
__global__ __launch_bounds__(256) void fft_u_kernel(const float* __restrict__ u,
                                                    float2* __restrict__ Uf) {
    int b = blockIdx.x;
    __shared__ float2 s[FFT_N];
    for (int i = threadIdx.x; i < FFT_N; i += 256)
        s[i] = make_float2(i < T ? u[(size_t)b * T + i] : 0.f, 0.f);
    fft_lds(s, threadIdx.x, -1.0f);
    for (int i = threadIdx.x; i < FFT_N; i += 256)
        Uf[(size_t)b * FFT_N + i] = s[i];
}

// ---------------- kernel 3: G[o] = W_h[o,:256] @ H ; Gf[o] = FFT_8192(G[o]) ----------------
__global__ __launch_bounds__(256) void g_fft_kernel(const float* __restrict__ Wh,
                                                    const float* __restrict__ H,
                                                    float2* __restrict__ Gf) {
    int o = blockIdx.x;   // 0..511
    __shared__ float2 s[FFT_N];
    const float* wrow = Wh + (size_t)o * HID;   // first 256 entries are the m-part
    float acc[16];
#pragma unroll
    for (int dd = 0; dd < 16; ++dd) acc[dd] = 0.f;
    for (int q = 0; q < 256; ++q) {
        float w = wrow[q];
        const float* hrow = H + (size_t)q * T;
#pragma unroll
        for (int dd = 0; dd < 16; ++dd)
            acc[dd] = fmaf(w, hrow[threadIdx.x + dd * 256], acc[dd]);
    }
#pragma unroll
    for (int dd = 0; dd < 16; ++dd)
        s[threadIdx.x + dd * 256] = make_float2(acc[dd], 0.f);
    for (int d = T + threadIdx.x; d < FFT_N; d += 256) s[d] = make_float2(0.f, 0.f);
    fft_lds(s, threadIdx.x, -1.0f);
    for (int f = threadIdx.x; f < FFT_N; f += 256)
        Gf[(size_t)o * FFT_N + f] = s[f];
}

// ---------------- kernel 4: out[r,o] = dot(x[r,:], W_h[o,256:])  (pre-activation) ----------------
__global__ __launch_bounds__(256) void xw_gemm_kernel(const float* __restrict__ x,
                                                      const float* __restrict__ Wh,
                                                      float* __restrict__ out) {
    __shared__ float As[64][65];   // [k][m]
    __shared__ float Bs[64][65];   // [k][n]
    int bm = blockIdx.x;           // 131072/64 = 2048
    int bn = blockIdx.y;           // 512/64 = 8
    int tid = threadIdx.x;
    int tx = tid & 15, ty = tid >> 4;
    int m0 = ty * 4, n0 = tx * 4;
    float acc[4][4] = {};
    for (int kc = 0; kc < IND; kc += 64) {
#pragma unroll
        for (int it = 0; it < 4; ++it) {
            int l = it * 1024 + tid * 4;
            int row = l >> 6, col = l & 63;
            float4 v = *(const float4*)(x + (size_t)(bm * 64 + row) * IND + kc + col);
            As[col + 0][row] = v.x; As[col + 1][row] = v.y;
            As[col + 2][row] = v.z; As[col + 3][row] = v.w;
        }
#pragma unroll
        for (int it = 0; it < 4; ++it) {
            int l = it * 1024 + tid * 4;
            int row = l >> 6, col = l & 63;
            float4 v = *(const float4*)(Wh + (size_t)(bn * 64 + row) * HID + 256 + kc + col);
            Bs[col + 0][row] = v.x; Bs[col + 1][row] = v.y;
            Bs[col + 2][row] = v.z; Bs[col + 3][row] = v.w;
        }
        __syncthreads();
#pragma unroll
        for (int k = 0; k < 64; ++k) {
            float a[4], b[4];
#pragma unroll
            for (int i = 0; i < 4; ++i) a[i] = As[k][m0 + i];
#pragma unroll
            for (int j = 0; j < 4; ++j) b[j] = Bs[k][n0 + j];
#pragma unroll
            for (int i = 0; i < 4; ++i)
#pragma unroll
                for (int j = 0; j < 4; ++j) acc[i][j] = fmaf(a[i], b[j], acc[i][j]);
        }
        __syncthreads();
    }
#pragma unroll
    for (int i = 0; i < 4; ++i) {
        size_t r = (size_t)(bm * 64 + m0 + i);
        float4 v = make_float4(acc[i][0], acc[i][1], acc[i][2], acc[i][3]);
        *(float4*)(out + r * HID + bn * 64 + n0) = v;
    }
}

// ---------------- kernel 5: per (b, o-pair): iFFT(U .* (G0 + i G1)), add, relu ----------------
__global__ __launch_bounds__(256) void conv_apply_kernel(const float2* __restrict__ Uf,
                                                         const float2* __restrict__ Gf,
                                                         float* __restrict__ out) {
    int p = blockIdx.x;   // 0..255  -> o0=2p, o1=2p+1
    int b = blockIdx.y;   // 0..31
    __shared__ float2 s[FFT_N];
    const float2* Ub = Uf + (size_t)b * FFT_N;
    const float2* G0 = Gf + (size_t)(2 * p) * FFT_N;
    const float2* G1 = Gf + (size_t)(2 * p + 1) * FFT_N;
    for (int f = threadIdx.x; f < FFT_N; f += 256) {
        float2 uv = Ub[f], g0 = G0[f], g1 = G1[f];
        float2 g = make_float2(g0.x - g1.y, g0.y + g1.x);   // g0 + i*g1
        s[f] = make_float2(uv.x * g.x - uv.y * g.y, uv.x * g.y + uv.y * g.x);
    }
    fft_lds(s, threadIdx.x, +1.0f);
    const float inv = 1.0f / (float)FFT_N;
    for (int t = threadIdx.x; t < T; t += 256) {
        size_t idx = ((size_t)(b * T + t)) * HID + 2 * p;
        float2 xw = *(const float2*)(out + idx);
        float v0 = fmaxf(fmaf(s[t].x, inv, xw.x), 0.f);
        float v1 = fmaxf(fmaf(s[t].y, inv, xw.y), 0.f);
        *(float2*)(out + idx) = make_float2(v0, v1);
        if (t == T - 1) {
            size_t hn = (size_t)BATCH * T * HID + (size_t)b * HID + 2 * p;
            *(float2*)(out + hn) = make_float2(v0, v1);
        }
    }
}

extern "C" void kernel_launch(void* const* d_in, const int* in_sizes, int n_in,
                              void* d_out, int out_size, void* d_ws, size_t ws_size,
                              hipStream_t stream) {
    const float* x  = (const float*)d_in[0];   // 32*4096*256
    const float* Wu = (const float*)d_in[1];   // 256
    const float* Wh = (const float*)d_in[2];   // 512*512
    const float* H  = (const float*)d_in[3];   // 256*4096
    float* out = (float*)d_out;

    char* ws = (char*)d_ws;
    float*  ws_u = (float*)ws;                                   // 131072 floats  (0.5 MB)
    float2* ws_U = (float2*)(ws + 524288);                       // 32*8192 float2 (2 MB)
    float2* ws_G = (float2*)(ws + 524288 + 2097152);             // 512*8192 float2 (32 MB)

    relu_u_kernel<<<BATCH * T / 4, 256, 0, stream>>>(x, Wu, ws_u);
    fft_u_kernel<<<BATCH, 256, 0, stream>>>(ws_u, ws_U);
    g_fft_kernel<<<HID, 256, 0, stream>>>(Wh, H, ws_G);
    xw_gemm_kernel<<<dim3(BATCH * T / 64, HID / 64), 256, 0, stream>>>(x, Wh, out);
    conv_apply_kernel<<<dim3(HID / 2, BATCH), 256, 0, stream>>>(ws_U, ws_G, out);
}

// Round 2
// 1598.737 us; speedup vs baseline: 1.5859x; 1.5859x over previous
//
#include <hip/hip_runtime.h>
#include <hip/hip_bf16.h>
#include <math.h>

// LMU-FFT: x(32,4096,256), W_u(1,256), W_h(512,512), H(256,4096) -> h(32,4096,512), h_n(32,512)
// Strategy: fold W_h[:, :256] into H: G = W_h[:,:256] @ H  (512 x 4096).
//   h[b,t,o] = relu( (u[b] * G[o])[t]  +  dot(x[b,t,:], W_h[o,256:]) )
// FFT convolution, N=8192. Forward FFTs use DIF (natural->bitrev), inverse uses
// DIT (bitrev->natural): pointwise products in bit-reversed order need no
// bit-reversal passes at all. LDS is SoA re[]/im[] to cut bank conflicts.
// x @ W_h[:,256:] is a bf16 MFMA GEMM (fp32 accumulate), conversion fused into staging.

#define BATCH 32
#define T     4096
#define IND   256
#define HID   512
#define FFT_N 8192
#define FFT_LOG 13

typedef __attribute__((ext_vector_type(8))) short short8;
typedef __attribute__((ext_vector_type(4))) float f32x4;

__device__ inline short f2bf(float f) {
    unsigned u = __float_as_uint(f);
    unsigned r = (u + 0x7FFFu + ((u >> 16) & 1u)) >> 16;
    return (short)r;
}

// ---------------- SoA LDS FFTs, 512 threads ----------------
// forward: natural input -> bit-reversed output (DIF)
__device__ void fft_dif_fwd(float* re, float* im) {
    __syncthreads();
    for (int st = FFT_LOG; st >= 1; --st) {
        int half = 1 << (st - 1);
        float fm = -(float)M_PI / (float)half;
        for (int k = threadIdx.x; k < FFT_N / 2; k += 512) {
            int j  = k & (half - 1);
            int i1 = ((k >> (st - 1)) << st) + j;
            int i2 = i1 + half;
            float sn, cs;
            __sincosf(fm * (float)j, &sn, &cs);
            float ar = re[i1], ai = im[i1];
            float br = re[i2], bi = im[i2];
            re[i1] = ar + br; im[i1] = ai + bi;
            float dr = ar - br, di = ai - bi;
            re[i2] = cs * dr - sn * di;
            im[i2] = cs * di + sn * dr;
        }
        __syncthreads();
    }
}
// inverse (unscaled): bit-reversed input -> natural output (DIT)
__device__ void fft_dit_inv(float* re, float* im) {
    __syncthreads();
    for (int st = 1; st <= FFT_LOG; ++st) {
        int half = 1 << (st - 1);
        float fm = (float)M_PI / (float)half;
        for (int k = threadIdx.x; k < FFT_N / 2; k += 512) {
            int j  = k & (half - 1);
            int i1 = ((k >> (st - 1)) << st) + j;
            int i2 = i1 + half;
            float sn, cs;
            __sincosf(fm * (float)j, &sn, &cs);
            float br = re[i2], bi = im[i2];
            float tr = cs * br - sn * bi;
            float ti = cs * bi + sn * br;
            float ar = re[i1], ai = im[i1];
            re[i1] = ar + tr; im[i1] = ai + ti;
            re[i2] = ar - tr; im[i2] = ai - ti;
        }
        __syncthreads();
    }
}

// ---------------- kernel 1: u[b,t] = relu(dot(x[b,t,:], W_u)) ----------------
__global__ __launch_bounds__(256) void relu_u_kernel(const float* __restrict__ x,
                                                     const float* __restrict__ Wu,
                                                     float* __restrict__ u) {
    int wave = threadIdx.x >> 6, lane = threadIdx.x & 63;
    int r = blockIdx.x * 4 + wave;
    const float4 xv = *(const float4*)(x + (size_t)r * IND + lane * 4);
    const float4 wv = *(const float4*)(Wu + lane * 4);
    float acc = xv.x * wv.x + xv.y * wv.y + xv.z * wv.z + xv.w * wv.w;
    for (int off = 32; off; off >>= 1) acc += __shfl_down(acc, off);
    if (lane == 0) u[r] = fmaxf(acc, 0.f);
}

// ---------------- kernel 2: U[b] = DIF-FFT(zero-pad u[b])  (bitrev order) ----------------
__global__ __launch_bounds__(512) void fft_u_kernel(const float* __restrict__ u,
                                                    float2* __restrict__ Uf) {
    int b = blockIdx.x;
    __shared__ float re[FFT_N];
    __shared__ float im[FFT_N];
    for (int i = threadIdx.x; i < FFT_N; i += 512) {
        re[i] = i < T ? u[(size_t)b * T + i] : 0.f;
        im[i] = 0.f;
    }
    fft_dif_fwd(re, im);
    for (int i = threadIdx.x; i < FFT_N; i += 512)
        Uf[(size_t)b * FFT_N + i] = make_float2(re[i], im[i]);
}

// ---------------- kernel 3: G[o] = W_h[o,:256] @ H ; Gf[o] = DIF-FFT(G[o]) ----------------
__global__ __launch_bounds__(512) void g_fft_kernel(const float* __restrict__ Wh,
                                                    const float* __restrict__ H,
                                                    float2* __restrict__ Gf) {
    int o = blockIdx.x;
    __shared__ float re[FFT_N];
    __shared__ float im[FFT_N];
    const float* wrow = Wh + (size_t)o * HID;
    float acc[8];
#pragma unroll
    for (int d = 0; d < 8; ++d) acc[d] = 0.f;
    for (int q = 0; q < 256; ++q) {
        float w = wrow[q];
        const float* hrow = H + (size_t)q * T;
#pragma unroll
        for (int d = 0; d < 8; ++d)
            acc[d] = fmaf(w, hrow[threadIdx.x + d * 512], acc[d]);
    }
#pragma unroll
    for (int d = 0; d < 8; ++d) {
        re[threadIdx.x + d * 512] = acc[d];
        im[threadIdx.x + d * 512] = 0.f;
    }
    for (int i = T + threadIdx.x; i < FFT_N; i += 512) { re[i] = 0.f; im[i] = 0.f; }
    fft_dif_fwd(re, im);
    for (int i = threadIdx.x; i < FFT_N; i += 512)
        Gf[(size_t)o * FFT_N + i] = make_float2(re[i], im[i]);
}

// ---------------- kernel 4: out[r,o] = dot(x[r,:], W_h[o,256:])  bf16 MFMA ----------------
__global__ __launch_bounds__(256) void xw_gemm_kernel(const float* __restrict__ x,
                                                      const float* __restrict__ Wh,
                                                      float* __restrict__ out) {
    // tile: 128(M) x 128(N), BK=32 (one MFMA K). 4 waves, each a 64x64 quadrant.
    __shared__ __align__(16) short Asl[4][128][8];   // [k-group][m][k-in-group]
    __shared__ __align__(16) short Bsl[4][128][8];   // [k-group][n][k-in-group]
    int bn = blockIdx.x;     // 0..3   (n fastest -> 4 blocks share the same x strip via L2)
    int bm = blockIdx.y;     // 0..1023
    int t = threadIdx.x;
    int wv = t >> 6, lane = t & 63;
    int wm = (wv & 1) * 64, wn = (wv >> 1) * 64;
    int ln = lane & 15, kg = lane >> 4;

    f32x4 acc[4][4] = {};
    int mrow = t >> 1, khalf = t & 1;     // staging assignment
    for (int kc = 0; kc < IND; kc += 32) {
        {
            const float* xr = x + ((size_t)(bm * 128 + mrow)) * IND + kc + khalf * 16;
            float4 v0 = *(const float4*)(xr + 0);
            float4 v1 = *(const float4*)(xr + 4);
            float4 v2 = *(const float4*)(xr + 8);
            float4 v3 = *(const float4*)(xr + 12);
            short8 s0 = { f2bf(v0.x), f2bf(v0.y), f2bf(v0.z), f2bf(v0.w),
                          f2bf(v1.x), f2bf(v1.y), f2bf(v1.z), f2bf(v1.w) };
            short8 s1 = { f2bf(v2.x), f2bf(v2.y), f2bf(v2.z), f2bf(v2.w),
                          f2bf(v3.x), f2bf(v3.y), f2bf(v3.z), f2bf(v3.w) };
            const float* wr = Wh + ((size_t)(bn * 128 + mrow)) * HID + 256 + kc + khalf * 16;
            float4 w0 = *(const float4*)(wr + 0);
            float4 w1 = *(const float4*)(wr + 4);
            float4 w2 = *(const float4*)(wr + 8);
            float4 w3 = *(const float4*)(wr + 12);
            short8 b0 = { f2bf(w0.x), f2bf(w0.y), f2bf(w0.z), f2bf(w0.w),
                          f2bf(w1.x), f2bf(w1.y), f2bf(w1.z), f2bf(w1.w) };
            short8 b1 = { f2bf(w2.x), f2bf(w2.y), f2bf(w2.z), f2bf(w2.w),
                          f2bf(w3.x), f2bf(w3.y), f2bf(w3.z), f2bf(w3.w) };
            __syncthreads();   // protect previous iteration's reads
            *(short8*)&Asl[khalf * 2 + 0][mrow][0] = s0;
            *(short8*)&Asl[khalf * 2 + 1][mrow][0] = s1;
            *(short8*)&Bsl[khalf * 2 + 0][mrow][0] = b0;
            *(short8*)&Bsl[khalf * 2 + 1][mrow][0] = b1;
            __syncthreads();
        }
        short8 af[4], bf[4];
#pragma unroll
        for (int i = 0; i < 4; ++i) af[i] = *(short8*)&Asl[kg][wm + i * 16 + ln][0];
#pragma unroll
        for (int j = 0; j < 4; ++j) bf[j] = *(short8*)&Bsl[kg][wn + j * 16 + ln][0];
#pragma unroll
        for (int i = 0; i < 4; ++i)
#pragma unroll
            for (int j = 0; j < 4; ++j)
                acc[i][j] = __builtin_amdgcn_mfma_f32_16x16x32_bf16(af[i], bf[j], acc[i][j], 0, 0, 0);
    }
#pragma unroll
    for (int i = 0; i < 4; ++i) {
#pragma unroll
        for (int j = 0; j < 4; ++j) {
#pragma unroll
            for (int r = 0; r < 4; ++r) {
                int row = bm * 128 + wm + i * 16 + (lane >> 4) * 4 + r;
                int col = bn * 128 + wn + j * 16 + (lane & 15);
                out[(size_t)row * HID + col] = acc[i][j][r];
            }
        }
    }
}

// ---------------- kernel 5: per (b, o-pair): iFFT(U .* (G0 + i G1)), add, relu ----------------
__global__ __launch_bounds__(512) void conv_apply_kernel(const float2* __restrict__ Uf,
                                                         const float2* __restrict__ Gf,
                                                         float* __restrict__ out) {
    int p = blockIdx.x;   // 0..255  -> o0=2p, o1=2p+1
    int b = blockIdx.y;   // 0..31
    __shared__ float re[FFT_N];
    __shared__ float im[FFT_N];
    const float2* Ub = Uf + (size_t)b * FFT_N;
    const float2* G0 = Gf + (size_t)(2 * p) * FFT_N;
    const float2* G1 = Gf + (size_t)(2 * p + 1) * FFT_N;
    for (int f = threadIdx.x; f < FFT_N; f += 512) {
        float2 uv = Ub[f], g0 = G0[f], g1 = G1[f];
        float gr = g0.x - g1.y, gi = g0.y + g1.x;     // g0 + i*g1
        re[f] = uv.x * gr - uv.y * gi;
        im[f] = uv.x * gi + uv.y * gr;
    }
    fft_dit_inv(re, im);
    const float inv = 1.0f / (float)FFT_N;
    for (int t = threadIdx.x; t < T; t += 512) {
        size_t idx = ((size_t)(b * T + t)) * HID + 2 * p;
        float2 xw = *(const float2*)(out + idx);
        float v0 = fmaxf(fmaf(re[t], inv, xw.x), 0.f);
        float v1 = fmaxf(fmaf(im[t], inv, xw.y), 0.f);
        *(float2*)(out + idx) = make_float2(v0, v1);
        if (t == T - 1) {
            size_t hn = (size_t)BATCH * T * HID + (size_t)b * HID + 2 * p;
            *(float2*)(out + hn) = make_float2(v0, v1);
        }
    }
}

extern "C" void kernel_launch(void* const* d_in, const int* in_sizes, int n_in,
                              void* d_out, int out_size, void* d_ws, size_t ws_size,
                              hipStream_t stream) {
    const float* x  = (const float*)d_in[0];   // 32*4096*256
    const float* Wu = (const float*)d_in[1];   // 256
    const float* Wh = (const float*)d_in[2];   // 512*512
    const float* H  = (const float*)d_in[3];   // 256*4096
    float* out = (float*)d_out;

    char* ws = (char*)d_ws;
    float*  ws_u = (float*)ws;                                   // 131072 floats  (0.5 MB)
    float2* ws_U = (float2*)(ws + 524288);                       // 32*8192 float2 (2 MB)
    float2* ws_G = (float2*)(ws + 524288 + 2097152);             // 512*8192 float2 (32 MB)

    relu_u_kernel<<<BATCH * T / 4, 256, 0, stream>>>(x, Wu, ws_u);
    fft_u_kernel<<<BATCH, 512, 0, stream>>>(ws_u, ws_U);
    g_fft_kernel<<<HID, 512, 0, stream>>>(Wh, H, ws_G);
    xw_gemm_kernel<<<dim3(HID / 128, BATCH * T / 128), 256, 0, stream>>>(x, Wh, out);
    conv_apply_kernel<<<dim3(HID / 2, BATCH), 512, 0, stream>>>(ws_U, ws_G, out);
}